// Round 7
// baseline (333.809 us; speedup 1.0000x reference)
//
#include <hip/hip_runtime.h>
#include <hip/hip_bf16.h>

#define NN 100000
#define NE 1600000
#define INF 256
#define OUTF 128
#define NHALF 50000
#define NBK ((NN + 127) / 128)           // 782 buckets of 128 nodes
#define CHUNK 4096
#define NBA ((NE + CHUNK - 1) / CHUNK)   // 391 chunks
#define NG256 ((NN + 255) / 256)         // 391 node-groups of 256

typedef __attribute__((ext_vector_type(8))) short short8;
typedef __attribute__((ext_vector_type(4))) float f32x4;
typedef __attribute__((ext_vector_type(4))) uint u32x4;

static __device__ __forceinline__ short f2bf(float f) {
    __hip_bfloat16 h = __float2bfloat16(f);
    return *reinterpret_cast<short*>(&h);
}

// ---------------------------------------------------------------------------
// Setup: block 0: wsv = W@a_src, wdv = W@a_dst;
// blocks 1..8: swizzled bf16 B fragments of W_em.
// ---------------------------------------------------------------------------
__global__ void k_setup(const float* __restrict__ W, const float* __restrict__ a,
                        const float* __restrict__ Wem,
                        float* __restrict__ wsv, float* __restrict__ wdv,
                        ushort* __restrict__ Bsw) {
    const int b = blockIdx.x, t = threadIdx.x;
    if (b == 0) {
        const float* Wr = W + (size_t)t * OUTF;
        float sa = 0.f, sb = 0.f;
        #pragma unroll 8
        for (int k = 0; k < OUTF; ++k) {
            float w = Wr[k];
            sa += w * a[k];
            sb += w * a[OUTF + k];
        }
        wsv[t] = sa;
        wdv[t] = sb;
    } else {
        const int kt = b - 1;
        for (int idx = t; idx < 4096; idx += 256) {
            const int ct = idx >> 9;
            const int lane = (idx >> 3) & 63;
            const int j = idx & 7;
            const int k = kt * 32 + (lane >> 4) * 8 + j;
            const int c = ct * 16 + (lane & 15);
            Bsw[((size_t)(kt * 8 + ct) * 64 + lane) * 8 + j] =
                (ushort)f2bf(Wem[(size_t)k * OUTF + c]);
        }
    }
}

// ---------------------------------------------------------------------------
// MFMA matmul: hem(bf16) = x @ W_em; fused f32 s1 = x.ws, s2 = x.wd.
// hem stored as 8 XCD-L2-resident TILES of 64-byte rows:
//   tile (fs 0..3, dh 0..1): [(fs*2+dh)*NHALF + (row - dh*NHALF)]*32 + cw
//   (features fs*32..+31 for rows in half dh; tile = 3.2 MB)
// ---------------------------------------------------------------------------
__global__ __launch_bounds__(256) void k_mm(
    const float* __restrict__ x, const ushort* __restrict__ Bsw,
    const float* __restrict__ wsv, const float* __restrict__ wdv,
    float* __restrict__ s1, float* __restrict__ s2, ushort* __restrict__ hem) {
    const int t = threadIdx.x;
    const int w = t >> 6, lane = t & 63;
    const int br = blockIdx.x * 64 + w * 16;
    const int r0 = lane & 15, kq = lane >> 4;
    const int row = br + r0;
    const int rowc = (row < NN) ? row : NN - 1;
    const float* xp = x + (size_t)rowc * INF + kq * 8;
    const short8* bp = reinterpret_cast<const short8*>(Bsw);

    f32x4 acc[8];
    #pragma unroll
    for (int ct = 0; ct < 8; ++ct) acc[ct] = (f32x4){0.f, 0.f, 0.f, 0.f};
    float sa = 0.f, sb = 0.f;

    #pragma unroll
    for (int kt = 0; kt < 8; ++kt) {
        const float4 a0 = *reinterpret_cast<const float4*>(xp + kt * 32);
        const float4 a1 = *reinterpret_cast<const float4*>(xp + kt * 32 + 4);
        const float4 w0 = *reinterpret_cast<const float4*>(wsv + kt * 32 + kq * 8);
        const float4 w1 = *reinterpret_cast<const float4*>(wsv + kt * 32 + kq * 8 + 4);
        const float4 u0 = *reinterpret_cast<const float4*>(wdv + kt * 32 + kq * 8);
        const float4 u1 = *reinterpret_cast<const float4*>(wdv + kt * 32 + kq * 8 + 4);
        sa += a0.x * w0.x + a0.y * w0.y + a0.z * w0.z + a0.w * w0.w
            + a1.x * w1.x + a1.y * w1.y + a1.z * w1.z + a1.w * w1.w;
        sb += a0.x * u0.x + a0.y * u0.y + a0.z * u0.z + a0.w * u0.w
            + a1.x * u1.x + a1.y * u1.y + a1.z * u1.z + a1.w * u1.w;
        short8 af;
        af[0] = f2bf(a0.x); af[1] = f2bf(a0.y); af[2] = f2bf(a0.z); af[3] = f2bf(a0.w);
        af[4] = f2bf(a1.x); af[5] = f2bf(a1.y); af[6] = f2bf(a1.z); af[7] = f2bf(a1.w);
        #pragma unroll
        for (int ct = 0; ct < 8; ++ct) {
            const short8 bf = bp[(size_t)(kt * 8 + ct) * 64 + lane];
            acc[ct] = __builtin_amdgcn_mfma_f32_16x16x32_bf16(af, bf, acc[ct], 0, 0, 0);
        }
    }

    sa += __shfl_xor(sa, 16); sa += __shfl_xor(sa, 32);
    sb += __shfl_xor(sb, 16); sb += __shfl_xor(sb, 32);
    if (kq == 0 && row < NN) { s1[row] = sa; s2[row] = sb; }

    #pragma unroll
    for (int ct = 0; ct < 8; ++ct) {
        const int fs = ct >> 1;
        const int cw = (ct & 1) * 16 + r0;
        #pragma unroll
        for (int i = 0; i < 4; ++i) {
            const int rr = br + kq * 4 + i;
            if (rr < NN) {
                const int dh = (rr >= NHALF) ? 1 : 0;
                const int np = rr - dh * NHALF;
                hem[((size_t)(fs * 2 + dh) * NHALF + np) * 32 + cw] =
                    (ushort)f2bf(acc[ct][i]);
            }
        }
    }
}

// ---------------------------------------------------------------------------
// Per-chunk per-bucket counts (LDS only, no global atomics).
// ---------------------------------------------------------------------------
__global__ __launch_bounds__(256) void k_cnt(
    const int* __restrict__ src, int* __restrict__ cntA) {
    __shared__ int cnt[NBK];
    const int t = threadIdx.x;
    const int c = blockIdx.x;
    const int e0 = c * CHUNK;
    for (int i = t; i < NBK; i += 256) cnt[i] = 0;
    __syncthreads();
    for (int i = t; i < CHUNK; i += 256) {
        const int e = e0 + i;
        if (e < NE) atomicAdd(&cnt[src[e] >> 7], 1);
    }
    __syncthreads();
    for (int i = t; i < NBK; i += 256) cntA[(size_t)c * NBK + i] = cnt[i];
}

// ---------------------------------------------------------------------------
// Per-bucket scan over chunks: baseA[c][b] = exclusive sum, bsumB[b] = total.
// ---------------------------------------------------------------------------
__global__ __launch_bounds__(512) void k_cscan(
    const int* __restrict__ cntA, int* __restrict__ baseA,
    int* __restrict__ bsumB) {
    __shared__ int sm[512];
    const int b = blockIdx.x;
    const int t = threadIdx.x;
    const int v = (t < NBA) ? cntA[(size_t)t * NBK + b] : 0;
    sm[t] = v;
    __syncthreads();
    for (int off = 1; off < 512; off <<= 1) {
        const int add = (t >= off) ? sm[t - off] : 0;
        __syncthreads();
        sm[t] += add;
        __syncthreads();
    }
    if (t < NBA) baseA[(size_t)t * NBK + b] = sm[t] - v;
    if (t == 511) bsumB[b] = sm[511];
}

// ---------------------------------------------------------------------------
// Bucket exclusive scan (1 block, 1024 threads, NBK=782) + sentinels.
// ---------------------------------------------------------------------------
__global__ __launch_bounds__(1024) void k_bbase(
    const int* __restrict__ bsumB, int* __restrict__ bbase,
    int* __restrict__ offs2) {
    __shared__ int sm[1024];
    const int t = threadIdx.x;
    const int v = (t < NBK) ? bsumB[t] : 0;
    sm[t] = v;
    __syncthreads();
    for (int off = 1; off < 1024; off <<= 1) {
        const int add = (t >= off) ? sm[t - off] : 0;
        __syncthreads();
        sm[t] += add;
        __syncthreads();
    }
    if (t < NBK) bbase[t] = sm[t] - v;
    if (t == 0) { bbase[NBK] = NE; offs2[2 * NN] = NE; }
}

// ---------------------------------------------------------------------------
// Pass A (fused edge_e): single-pass deterministic scatter into bucket runs.
// ebA record: { (dst<<7) | (src&127), vq },  vq = round((exp(sig(ee))-1)*16384)
// ---------------------------------------------------------------------------
__global__ __launch_bounds__(256) void k_binA(
    const int* __restrict__ src, const int* __restrict__ dst,
    const float* __restrict__ s1, const float* __restrict__ s2,
    float* __restrict__ ee_out, const int* __restrict__ bbase,
    const int* __restrict__ baseA, int2* __restrict__ ebA) {
    __shared__ int base[NBK];
    __shared__ int cnt[NBK];
    const int t = threadIdx.x;
    const int c = blockIdx.x;
    const int e0 = c * CHUNK;
    for (int i = t; i < NBK; i += 256) {
        base[i] = bbase[i] + baseA[(size_t)c * NBK + i];
        cnt[i] = 0;
    }
    __syncthreads();
    for (int i = t; i < CHUNK; i += 256) {
        const int e = e0 + i;
        if (e < NE) {
            const int s = src[e], d = dst[e];
            const float ee = s1[s] + s2[d];
            ee_out[e] = ee;
            const float ob = 1.f / (1.f + __expf(-ee));
            const float v = __expf(ob);                   // in (1, e)
            int vq = (int)((v - 1.f) * 16384.f + 0.5f);   // <= 28147
            vq = (vq > 32767) ? 32767 : vq;
            const int bk = s >> 7;
            const int r = atomicAdd(&cnt[bk], 1);
            ebA[base[bk] + r] = make_int2((d << 7) | (s & 127), vq);
        }
    }
}

// ---------------------------------------------------------------------------
// Pass B: one block per bucket. 256 virtual bins = (node-in-bucket, dst-half).
// CSR offs2[2n+dh]; record = (dp<<15) | attq, dp = dst - dh*50000.
//   attq = round((16384+vq) * 32767 / (16384*cnt + vqsum))  (exact ints)
// ---------------------------------------------------------------------------
__global__ __launch_bounds__(256) void k_sortB(
    const int* __restrict__ bbase, const int2* __restrict__ ebA,
    uint* __restrict__ ebB, int* __restrict__ offs2) {
    __shared__ int cnt[256];
    __shared__ int sum[128];
    __shared__ int sm[256];
    __shared__ int cur[256];
    __shared__ float fsl[128];
    const int b = blockIdx.x, t = threadIdx.x;
    const int n0 = b << 7;
    const int lo = bbase[b];
    const int hi = bbase[b + 1];
    cnt[t] = 0;
    if (t < 128) sum[t] = 0;
    __syncthreads();
    for (int i = lo + t; i < hi; i += 256) {
        const int2 r = ebA[i];
        const int sidx = r.x & 127;
        const uint d = ((unsigned)r.x) >> 7;
        const int vid = (sidx << 1) | (d >= (uint)NHALF ? 1 : 0);
        atomicAdd(&cnt[vid], 1);
        atomicAdd(&sum[sidx], r.y);
    }
    __syncthreads();
    const int v = cnt[t];
    sm[t] = v;
    __syncthreads();
    for (int off = 1; off < 256; off <<= 1) {
        const int add = (t >= off) ? sm[t - off] : 0;
        __syncthreads();
        sm[t] += add;
        __syncthreads();
    }
    const int excl = sm[t] - v;
    cur[t] = excl;
    if (n0 + (t >> 1) < NN) offs2[n0 * 2 + t] = lo + excl;
    if (t < 128) {
        const int c = cnt[2 * t] + cnt[2 * t + 1];
        fsl[t] = (c > 0) ? 32767.f / (float)(c * 16384 + sum[t]) : 0.f;
    }
    __syncthreads();
    for (int i = lo + t; i < hi; i += 256) {
        const int2 r = ebA[i];
        const int sidx = r.x & 127;
        const uint d = ((unsigned)r.x) >> 7;
        const int dh = (d >= (uint)NHALF) ? 1 : 0;
        const uint dp = d - (uint)(dh * NHALF);
        const float att = (float)(16384 + r.y) * fsl[sidx];
        int attq = (int)(att + 0.5f);
        attq = (attq > 32767) ? 32767 : attq;
        const int p = atomicAdd(&cur[(sidx << 1) | dh], 1);
        ebB[lo + p] = (dp << 15) | (uint)attq;
    }
}

// ---------------------------------------------------------------------------
// Aggregation v3: 1 lane per (node, fs, dh), 64 B row per edge via 4
// independent 16 B loads (4-deep MLP/edge, decode once). nt record loads so
// streams don't evict the 3.2 MB hem tile from the XCD's L2.
// mode 0 (concurrent): grid 8*NG256, tile8=blockIdx&7 -> (fs,dh); dh=0 ->
//   out0, dh=1 -> tmp (combined later). mode 1/2 (serial fallback, no tmp):
//   grid 4*NG256, fs=blockIdx&3 (tile on 2 XCDs), dh=mode-1, mode2 = RMW.
// ---------------------------------------------------------------------------
static __device__ __forceinline__ void accum(
    float wv, u32x4 u, f32x4& lo, f32x4& hi) {
    const u32x4 l = u << 16;
    const u32x4 h = u & 0xffff0000u;
    lo += wv * __builtin_bit_cast(f32x4, l);
    hi += wv * __builtin_bit_cast(f32x4, h);
}

static __device__ __forceinline__ void edge_accum(
    const char* hbase, uint r,
    f32x4& lo0, f32x4& hi0, f32x4& lo1, f32x4& hi1,
    f32x4& lo2, f32x4& hi2, f32x4& lo3, f32x4& hi3) {
    const float wv = (float)(r & 0x7fffu);
    const char* p = hbase + ((size_t)(r >> 15) << 6);
    const u32x4 u0 = *reinterpret_cast<const u32x4*>(p);
    const u32x4 u1 = *reinterpret_cast<const u32x4*>(p + 16);
    const u32x4 u2 = *reinterpret_cast<const u32x4*>(p + 32);
    const u32x4 u3 = *reinterpret_cast<const u32x4*>(p + 48);
    accum(wv, u0, lo0, hi0);
    accum(wv, u1, lo1, hi1);
    accum(wv, u2, lo2, hi2);
    accum(wv, u3, lo3, hi3);
}

__global__ __launch_bounds__(256) void k_aggregate(
    const uint* __restrict__ eb, const int* __restrict__ offs2,
    const ushort* __restrict__ hem, float* __restrict__ out0,
    float* __restrict__ tmp, const int mode) {
    int fs, dh, gb;
    float* outp = out0;
    bool rmw = false;
    if (mode == 0) {
        const int t8 = blockIdx.x & 7;
        fs = t8 >> 1;
        dh = t8 & 1;
        gb = blockIdx.x >> 3;
        if (dh) outp = tmp;
    } else {
        fs = blockIdx.x & 3;
        dh = mode - 1;
        gb = blockIdx.x >> 2;
        rmw = (mode == 2);
    }
    const int node = gb * 256 + threadIdx.x;
    if (node >= NN) return;
    const char* hbase = reinterpret_cast<const char*>(hem)
                      + (size_t)(fs * 2 + dh) * NHALF * 64;
    const int beg = offs2[node * 2 + dh];
    const int end = offs2[node * 2 + dh + 1];

    f32x4 lo0 = {0,0,0,0}, hi0 = {0,0,0,0}, lo1 = {0,0,0,0}, hi1 = {0,0,0,0};
    f32x4 lo2 = {0,0,0,0}, hi2 = {0,0,0,0}, lo3 = {0,0,0,0}, hi3 = {0,0,0,0};

    int j = beg;
    for (; j + 2 <= end; j += 2) {
        const uint r0 = __builtin_nontemporal_load(eb + j);
        const uint r1 = __builtin_nontemporal_load(eb + j + 1);
        edge_accum(hbase, r0, lo0, hi0, lo1, hi1, lo2, hi2, lo3, hi3);
        edge_accum(hbase, r1, lo0, hi0, lo1, hi1, lo2, hi2, lo3, hi3);
    }
    if (j < end) {
        const uint r0 = __builtin_nontemporal_load(eb + j);
        edge_accum(hbase, r0, lo0, hi0, lo1, hi1, lo2, hi2, lo3, hi3);
    }
    const float s = 1.f / 32767.f;
    float* op = outp + (size_t)node * OUTF + fs * 32;
    f32x4 o0 = {lo0[0]*s, hi0[0]*s, lo0[1]*s, hi0[1]*s};
    f32x4 o1 = {lo0[2]*s, hi0[2]*s, lo0[3]*s, hi0[3]*s};
    f32x4 o2 = {lo1[0]*s, hi1[0]*s, lo1[1]*s, hi1[1]*s};
    f32x4 o3 = {lo1[2]*s, hi1[2]*s, lo1[3]*s, hi1[3]*s};
    f32x4 o4 = {lo2[0]*s, hi2[0]*s, lo2[1]*s, hi2[1]*s};
    f32x4 o5 = {lo2[2]*s, hi2[2]*s, lo2[3]*s, hi2[3]*s};
    f32x4 o6 = {lo3[0]*s, hi3[0]*s, lo3[1]*s, hi3[1]*s};
    f32x4 o7 = {lo3[2]*s, hi3[2]*s, lo3[3]*s, hi3[3]*s};
    f32x4* vp = reinterpret_cast<f32x4*>(op);
    if (!rmw) {
        __builtin_nontemporal_store(o0, vp);
        __builtin_nontemporal_store(o1, vp + 1);
        __builtin_nontemporal_store(o2, vp + 2);
        __builtin_nontemporal_store(o3, vp + 3);
        __builtin_nontemporal_store(o4, vp + 4);
        __builtin_nontemporal_store(o5, vp + 5);
        __builtin_nontemporal_store(o6, vp + 6);
        __builtin_nontemporal_store(o7, vp + 7);
    } else {
        vp[0] += o0; vp[1] += o1; vp[2] += o2; vp[3] += o3;
        vp[4] += o4; vp[5] += o5; vp[6] += o6; vp[7] += o7;
    }
}

// ---------------------------------------------------------------------------
// out0 += tmp (streaming, nt both sides). 12.8M floats = 3.2M f32x4.
// ---------------------------------------------------------------------------
__global__ __launch_bounds__(256) void k_combine(
    float* __restrict__ out0, const float* __restrict__ tmp) {
    const size_t i = (size_t)blockIdx.x * 256 + threadIdx.x;
    f32x4* op = reinterpret_cast<f32x4*>(out0) + i;
    const f32x4* tp = reinterpret_cast<const f32x4*>(tmp) + i;
    f32x4 a = __builtin_nontemporal_load(op);
    f32x4 b = __builtin_nontemporal_load(tp);
    a += b;
    __builtin_nontemporal_store(a, op);
}

// ---------------------------------------------------------------------------
extern "C" void kernel_launch(void* const* d_in, const int* in_sizes, int n_in,
                              void* d_out, int out_size, void* d_ws, size_t ws_size,
                              hipStream_t stream) {
    const float* x   = (const float*)d_in[0];
    const int* eidx  = (const int*)d_in[1];
    const float* W   = (const float*)d_in[2];
    const float* a   = (const float*)d_in[3];
    const float* Wem = (const float*)d_in[4];

    const int* src = eidx;
    const int* dst = eidx + NE;

    float* out0 = (float*)d_out;            // h_prime: NN*128
    float* out1 = out0 + (size_t)NN * OUTF; // edge_e: NE

    // workspace layout (~49 MB base + 51.2 MB tmp if it fits)
    float* wsv   = (float*)d_ws;                     // 256
    float* wdv   = wsv + 256;                        // 256
    float* s1    = wdv + 256;                        // NN
    float* s2    = s1 + NN;                          // NN
    ushort* hem  = (ushort*)(s2 + NN);               // NN*128 bf16 (tiled layout)
    ushort* Bsw  = hem + (size_t)NN * OUTF;          // 32768
    int* offs2   = (int*)(Bsw + 32768);              // 2*NN+4 (sentinel + pad)
    int* bsumB   = offs2 + 2 * NN + 4;               // NBK (pad to 784)
    int* bbase   = bsumB + 784;                      // NBK+1 (pad to 788)
    int* cntA    = bbase + 788;                      // NBA*NBK
    int* baseA   = cntA + NBA * NBK;                 // NBA*NBK
    int2* ebA    = (int2*)(baseA + NBA * NBK);       // NE * 8B
    uint* ebB    = (uint*)(ebA + NE);                // NE * 4B
    float* tmp   = (float*)(ebB + NE);               // NN*OUTF (dh=1 partials)

    const size_t needed =
        (size_t)((char*)(tmp + (size_t)NN * OUTF) - (char*)d_ws);
    const bool conc = ws_size >= needed;

    hipLaunchKernelGGL(k_setup, dim3(9), dim3(256), 0, stream,
                       W, a, Wem, wsv, wdv, Bsw);
    hipLaunchKernelGGL(k_mm, dim3((NN + 63) / 64), dim3(256), 0, stream,
                       x, Bsw, wsv, wdv, s1, s2, hem);
    hipLaunchKernelGGL(k_cnt, dim3(NBA), dim3(256), 0, stream, src, cntA);
    hipLaunchKernelGGL(k_cscan, dim3(NBK), dim3(512), 0, stream, cntA, baseA, bsumB);
    hipLaunchKernelGGL(k_bbase, dim3(1), dim3(1024), 0, stream, bsumB, bbase, offs2);
    hipLaunchKernelGGL(k_binA, dim3(NBA), dim3(256), 0, stream,
                       src, dst, s1, s2, out1, bbase, baseA, ebA);
    hipLaunchKernelGGL(k_sortB, dim3(NBK), dim3(256), 0, stream,
                       bbase, ebA, ebB, offs2);
    if (conc) {
        hipLaunchKernelGGL(k_aggregate, dim3(8 * NG256), dim3(256), 0, stream,
                           ebB, offs2, hem, out0, tmp, 0);
        hipLaunchKernelGGL(k_combine, dim3((NN * OUTF) / 4 / 256), dim3(256),
                           0, stream, out0, tmp);
    } else {
        hipLaunchKernelGGL(k_aggregate, dim3(4 * NG256), dim3(256), 0, stream,
                           ebB, offs2, hem, out0, out0, 1);
        hipLaunchKernelGGL(k_aggregate, dim3(4 * NG256), dim3(256), 0, stream,
                           ebB, offs2, hem, out0, out0, 2);
    }
}

// Round 8
// 195.989 us; speedup vs baseline: 1.7032x; 1.7032x over previous
//
#include <hip/hip_runtime.h>
#include <hip/hip_bf16.h>

#define NN 100000
#define NE 1600000
#define INF 256
#define OUTF 128
#define NBK ((NN + 127) / 128)           // 782 buckets of 128 nodes
#define CHUNK 4096
#define NBA ((NE + CHUNK - 1) / CHUNK)   // 391 chunks
#define NGRP (NN / 32)                   // 3125 (exact)

typedef __attribute__((ext_vector_type(8))) short short8;
typedef __attribute__((ext_vector_type(4))) float f32x4;

static __device__ __forceinline__ short f2bf(float f) {
    __hip_bfloat16 h = __float2bfloat16(f);
    return *reinterpret_cast<short*>(&h);
}

// ---------------------------------------------------------------------------
// Setup: block 0: wsv = W@a_src, wdv = W@a_dst;
// blocks 1..8: swizzled bf16 B fragments of W_em.
// ---------------------------------------------------------------------------
__global__ void k_setup(const float* __restrict__ W, const float* __restrict__ a,
                        const float* __restrict__ Wem,
                        float* __restrict__ wsv, float* __restrict__ wdv,
                        ushort* __restrict__ Bsw) {
    const int b = blockIdx.x, t = threadIdx.x;
    if (b == 0) {
        const float* Wr = W + (size_t)t * OUTF;
        float sa = 0.f, sb = 0.f;
        #pragma unroll 8
        for (int k = 0; k < OUTF; ++k) {
            float w = Wr[k];
            sa += w * a[k];
            sb += w * a[OUTF + k];
        }
        wsv[t] = sa;
        wdv[t] = sb;
    } else {
        const int kt = b - 1;
        for (int idx = t; idx < 4096; idx += 256) {
            const int ct = idx >> 9;
            const int lane = (idx >> 3) & 63;
            const int j = idx & 7;
            const int k = kt * 32 + (lane >> 4) * 8 + j;
            const int c = ct * 16 + (lane & 15);
            Bsw[((size_t)(kt * 8 + ct) * 64 + lane) * 8 + j] =
                (ushort)f2bf(Wem[(size_t)k * OUTF + c]);
        }
    }
}

// ---------------------------------------------------------------------------
// MFMA matmul: hem(bf16) = x @ W_em; fused f32 s1 = x.ws, s2 = x.wd.
// hem SLICE-MAJOR (R1 layout, FETCH=52MB proven): 8 slices of 16 features,
//   hem[((size_t)ct*NN + row)*16 + c16], slice = contiguous 3.2 MB.
// ---------------------------------------------------------------------------
__global__ __launch_bounds__(256) void k_mm(
    const float* __restrict__ x, const ushort* __restrict__ Bsw,
    const float* __restrict__ wsv, const float* __restrict__ wdv,
    float* __restrict__ s1, float* __restrict__ s2, ushort* __restrict__ hem) {
    const int t = threadIdx.x;
    const int w = t >> 6, lane = t & 63;
    const int br = blockIdx.x * 64 + w * 16;
    const int r0 = lane & 15, kq = lane >> 4;
    const int row = br + r0;
    const int rowc = (row < NN) ? row : NN - 1;
    const float* xp = x + (size_t)rowc * INF + kq * 8;
    const short8* bp = reinterpret_cast<const short8*>(Bsw);

    f32x4 acc[8];
    #pragma unroll
    for (int ct = 0; ct < 8; ++ct) acc[ct] = (f32x4){0.f, 0.f, 0.f, 0.f};
    float sa = 0.f, sb = 0.f;

    #pragma unroll
    for (int kt = 0; kt < 8; ++kt) {
        const float4 a0 = *reinterpret_cast<const float4*>(xp + kt * 32);
        const float4 a1 = *reinterpret_cast<const float4*>(xp + kt * 32 + 4);
        const float4 w0 = *reinterpret_cast<const float4*>(wsv + kt * 32 + kq * 8);
        const float4 w1 = *reinterpret_cast<const float4*>(wsv + kt * 32 + kq * 8 + 4);
        const float4 u0 = *reinterpret_cast<const float4*>(wdv + kt * 32 + kq * 8);
        const float4 u1 = *reinterpret_cast<const float4*>(wdv + kt * 32 + kq * 8 + 4);
        sa += a0.x * w0.x + a0.y * w0.y + a0.z * w0.z + a0.w * w0.w
            + a1.x * w1.x + a1.y * w1.y + a1.z * w1.z + a1.w * w1.w;
        sb += a0.x * u0.x + a0.y * u0.y + a0.z * u0.z + a0.w * u0.w
            + a1.x * u1.x + a1.y * u1.y + a1.z * u1.z + a1.w * u1.w;
        short8 af;
        af[0] = f2bf(a0.x); af[1] = f2bf(a0.y); af[2] = f2bf(a0.z); af[3] = f2bf(a0.w);
        af[4] = f2bf(a1.x); af[5] = f2bf(a1.y); af[6] = f2bf(a1.z); af[7] = f2bf(a1.w);
        #pragma unroll
        for (int ct = 0; ct < 8; ++ct) {
            const short8 bf = bp[(size_t)(kt * 8 + ct) * 64 + lane];
            acc[ct] = __builtin_amdgcn_mfma_f32_16x16x32_bf16(af, bf, acc[ct], 0, 0, 0);
        }
    }

    sa += __shfl_xor(sa, 16); sa += __shfl_xor(sa, 32);
    sb += __shfl_xor(sb, 16); sb += __shfl_xor(sb, 32);
    if (kq == 0 && row < NN) { s1[row] = sa; s2[row] = sb; }

    #pragma unroll
    for (int ct = 0; ct < 8; ++ct) {
        #pragma unroll
        for (int i = 0; i < 4; ++i) {
            const int rr = br + kq * 4 + i;
            if (rr < NN)
                hem[((size_t)ct * NN + rr) * 16 + r0] = (ushort)f2bf(acc[ct][i]);
        }
    }
}

// ---------------------------------------------------------------------------
// Per-chunk per-bucket counts (LDS only, no global atomics).
// ---------------------------------------------------------------------------
__global__ __launch_bounds__(256) void k_cnt(
    const int* __restrict__ src, int* __restrict__ cntA) {
    __shared__ int cnt[NBK];
    const int t = threadIdx.x;
    const int c = blockIdx.x;
    const int e0 = c * CHUNK;
    for (int i = t; i < NBK; i += 256) cnt[i] = 0;
    __syncthreads();
    for (int i = t; i < CHUNK; i += 256) {
        const int e = e0 + i;
        if (e < NE) atomicAdd(&cnt[src[e] >> 7], 1);
    }
    __syncthreads();
    for (int i = t; i < NBK; i += 256) cntA[(size_t)c * NBK + i] = cnt[i];
}

// ---------------------------------------------------------------------------
// Per-bucket scan over chunks: baseA[c][b] = exclusive sum, bsumB[b] = total.
// ---------------------------------------------------------------------------
__global__ __launch_bounds__(512) void k_cscan(
    const int* __restrict__ cntA, int* __restrict__ baseA,
    int* __restrict__ bsumB) {
    __shared__ int sm[512];
    const int b = blockIdx.x;
    const int t = threadIdx.x;
    const int v = (t < NBA) ? cntA[(size_t)t * NBK + b] : 0;
    sm[t] = v;
    __syncthreads();
    for (int off = 1; off < 512; off <<= 1) {
        const int add = (t >= off) ? sm[t - off] : 0;
        __syncthreads();
        sm[t] += add;
        __syncthreads();
    }
    if (t < NBA) baseA[(size_t)t * NBK + b] = sm[t] - v;
    if (t == 511) bsumB[b] = sm[511];
}

// ---------------------------------------------------------------------------
// Bucket exclusive scan (1 block, 1024 threads, NBK=782) + sentinels.
// ---------------------------------------------------------------------------
__global__ __launch_bounds__(1024) void k_bbase(
    const int* __restrict__ bsumB, int* __restrict__ bbase,
    int* __restrict__ offs) {
    __shared__ int sm[1024];
    const int t = threadIdx.x;
    const int v = (t < NBK) ? bsumB[t] : 0;
    sm[t] = v;
    __syncthreads();
    for (int off = 1; off < 1024; off <<= 1) {
        const int add = (t >= off) ? sm[t - off] : 0;
        __syncthreads();
        sm[t] += add;
        __syncthreads();
    }
    if (t < NBK) bbase[t] = sm[t] - v;
    if (t == 0) { bbase[NBK] = NE; offs[NN] = NE; }
}

// ---------------------------------------------------------------------------
// Pass A (fused edge_e): single-pass deterministic scatter into bucket runs.
// ebA record: { (dst<<7) | (src&127), vq },  vq = round((exp(sig(ee))-1)*16384)
// ---------------------------------------------------------------------------
__global__ __launch_bounds__(256) void k_binA(
    const int* __restrict__ src, const int* __restrict__ dst,
    const float* __restrict__ s1, const float* __restrict__ s2,
    float* __restrict__ ee_out, const int* __restrict__ bbase,
    const int* __restrict__ baseA, int2* __restrict__ ebA) {
    __shared__ int base[NBK];
    __shared__ int cnt[NBK];
    const int t = threadIdx.x;
    const int c = blockIdx.x;
    const int e0 = c * CHUNK;
    for (int i = t; i < NBK; i += 256) {
        base[i] = bbase[i] + baseA[(size_t)c * NBK + i];
        cnt[i] = 0;
    }
    __syncthreads();
    for (int i = t; i < CHUNK; i += 256) {
        const int e = e0 + i;
        if (e < NE) {
            const int s = src[e], d = dst[e];
            const float ee = s1[s] + s2[d];
            ee_out[e] = ee;
            const float ob = 1.f / (1.f + __expf(-ee));
            const float v = __expf(ob);                   // in (1, e)
            int vq = (int)((v - 1.f) * 16384.f + 0.5f);   // <= 28147
            vq = (vq > 32767) ? 32767 : vq;
            const int bk = s >> 7;
            const int r = atomicAdd(&cnt[bk], 1);
            ebA[base[bk] + r] = make_int2((d << 7) | (s & 127), vq);
        }
    }
}

// ---------------------------------------------------------------------------
// Pass B: one block per bucket. Pass 1: LDS per-node count + vq-sum over the
// contiguous bucket run, 128-scan -> per-node CSR offsets (written to offs[])
// and folded 1/denominator. Pass 2: scatter 4-byte records (dst<<15)|attq,
//   attq = round((16384+vq) * 32767 / (16384*cnt + vqsum))  (exact ints)
// ---------------------------------------------------------------------------
__global__ __launch_bounds__(256) void k_sortB(
    const int* __restrict__ bbase, const int2* __restrict__ ebA,
    uint* __restrict__ ebB, int* __restrict__ offs) {
    __shared__ int cnt[128];
    __shared__ int sum[128];
    __shared__ int sm[128];
    __shared__ int cur[128];
    __shared__ float fsl[128];
    const int b = blockIdx.x, t = threadIdx.x;
    const int n0 = b << 7;
    const int lo = bbase[b];
    const int hi = bbase[b + 1];
    if (t < 128) { cnt[t] = 0; sum[t] = 0; }
    __syncthreads();
    for (int i = lo + t; i < hi; i += 256) {
        const int2 r = ebA[i];
        const int sidx = r.x & 127;
        atomicAdd(&cnt[sidx], 1);
        atomicAdd(&sum[sidx], r.y);
    }
    __syncthreads();
    const int v = (t < 128) ? cnt[t] : 0;
    if (t < 128) sm[t] = v;
    __syncthreads();
    for (int off = 1; off < 128; off <<= 1) {
        int add = 0;
        if (t < 128 && t >= off) add = sm[t - off];
        __syncthreads();
        if (t < 128) sm[t] += add;
        __syncthreads();
    }
    if (t < 128) {
        const int excl = sm[t] - v;
        cur[t] = excl;
        const int node = n0 + t;
        if (node < NN) offs[node] = lo + excl;
        fsl[t] = (v > 0) ? 32767.f / (float)(v * 16384 + sum[t]) : 0.f;
    }
    __syncthreads();
    for (int i = lo + t; i < hi; i += 256) {
        const int2 r = ebA[i];
        const int sidx = r.x & 127;
        const uint d = ((unsigned)r.x) >> 7;
        const float att = (float)(16384 + r.y) * fsl[sidx];
        int attq = (int)(att + 0.5f);
        attq = (attq > 32767) ? 32767 : attq;
        const int p = atomicAdd(&cur[sidx], 1);
        ebB[lo + p] = (d << 15) | (uint)attq;
    }
}

// ---------------------------------------------------------------------------
// Aggregation: R1 structure (FETCH=52MB proven) + attq records (VALU cheap).
// slice = blockIdx&7 -> XCD-pinned 3.2 MB hem slice; grid 8*3125 = 25000
// blocks (high TLP). Wave = 8 nodes x 8 feature-pair lanes; per lane-edge:
// 4 B record (broadcast across the node's 8 lanes) + 4 B gather; decode =
// and+cvt+2 fma. No reduction needed (lane owns its feature pair);
// attention prefolded so epilogue is a single scale.
// ---------------------------------------------------------------------------
__global__ __launch_bounds__(256) void k_aggregate(
    const uint* __restrict__ eb, const int* __restrict__ offs,
    const ushort* __restrict__ hem, float* __restrict__ out0) {
    const int slice = blockIdx.x & 7;
    const int grp = blockIdx.x >> 3;
    const int t = threadIdx.x;
    const int node = grp * 32 + (t >> 3);    // NN = 32*NGRP exactly
    const int f = t & 7;                     // feature-pair within slice
    const uint* hemS = reinterpret_cast<const uint*>(hem)
                     + (size_t)slice * NN * 8 + f;
    const int beg = offs[node];
    const int end = offs[node + 1];

    float a0 = 0.f, a1 = 0.f;
    int j = beg;
    for (; j + 4 <= end; j += 4) {
        const uint r0 = eb[j];
        const uint r1 = eb[j + 1];
        const uint r2 = eb[j + 2];
        const uint r3 = eb[j + 3];
        const float w0 = (float)(r0 & 0x7fffu);
        const float w1 = (float)(r1 & 0x7fffu);
        const float w2 = (float)(r2 & 0x7fffu);
        const float w3 = (float)(r3 & 0x7fffu);
        const uint u0 = hemS[(size_t)(r0 >> 15) * 8];
        const uint u1 = hemS[(size_t)(r1 >> 15) * 8];
        const uint u2 = hemS[(size_t)(r2 >> 15) * 8];
        const uint u3 = hemS[(size_t)(r3 >> 15) * 8];
        a0 += w0 * __uint_as_float(u0 << 16) + w1 * __uint_as_float(u1 << 16)
            + w2 * __uint_as_float(u2 << 16) + w3 * __uint_as_float(u3 << 16);
        a1 += w0 * __uint_as_float(u0 & 0xffff0000u)
            + w1 * __uint_as_float(u1 & 0xffff0000u)
            + w2 * __uint_as_float(u2 & 0xffff0000u)
            + w3 * __uint_as_float(u3 & 0xffff0000u);
    }
    for (; j < end; ++j) {
        const uint r0 = eb[j];
        const float w0 = (float)(r0 & 0x7fffu);
        const uint u0 = hemS[(size_t)(r0 >> 15) * 8];
        a0 += w0 * __uint_as_float(u0 << 16);
        a1 += w0 * __uint_as_float(u0 & 0xffff0000u);
    }
    const float s = 1.f / 32767.f;
    float2 o;
    o.x = a0 * s;
    o.y = a1 * s;
    *reinterpret_cast<float2*>(out0 + (size_t)node * OUTF + slice * 16 + f * 2) = o;
}

// ---------------------------------------------------------------------------
extern "C" void kernel_launch(void* const* d_in, const int* in_sizes, int n_in,
                              void* d_out, int out_size, void* d_ws, size_t ws_size,
                              hipStream_t stream) {
    const float* x   = (const float*)d_in[0];
    const int* eidx  = (const int*)d_in[1];
    const float* W   = (const float*)d_in[2];
    const float* a   = (const float*)d_in[3];
    const float* Wem = (const float*)d_in[4];

    const int* src = eidx;
    const int* dst = eidx + NE;

    float* out0 = (float*)d_out;            // h_prime: NN*128
    float* out1 = out0 + (size_t)NN * OUTF; // edge_e: NE

    // workspace layout (~49 MB), 16B-aligned chunks
    float* wsv   = (float*)d_ws;                     // 256
    float* wdv   = wsv + 256;                        // 256
    float* s1    = wdv + 256;                        // NN
    float* s2    = s1 + NN;                          // NN
    ushort* hem  = (ushort*)(s2 + NN);               // NN*128 bf16 (slice-major)
    ushort* Bsw  = hem + (size_t)NN * OUTF;          // 32768
    int* offs    = (int*)(Bsw + 32768);              // NN+4 (sentinel + pad)
    int* bsumB   = offs + NN + 4;                    // NBK (pad to 784)
    int* bbase   = bsumB + 784;                      // NBK+1 (pad to 788)
    int* cntA    = bbase + 788;                      // NBA*NBK
    int* baseA   = cntA + NBA * NBK;                 // NBA*NBK
    int2* ebA    = (int2*)(baseA + NBA * NBK);       // NE * 8B
    uint* ebB    = (uint*)(ebA + NE);                // NE * 4B

    hipLaunchKernelGGL(k_setup, dim3(9), dim3(256), 0, stream,
                       W, a, Wem, wsv, wdv, Bsw);
    hipLaunchKernelGGL(k_mm, dim3((NN + 63) / 64), dim3(256), 0, stream,
                       x, Bsw, wsv, wdv, s1, s2, hem);
    hipLaunchKernelGGL(k_cnt, dim3(NBA), dim3(256), 0, stream, src, cntA);
    hipLaunchKernelGGL(k_cscan, dim3(NBK), dim3(512), 0, stream, cntA, baseA, bsumB);
    hipLaunchKernelGGL(k_bbase, dim3(1), dim3(1024), 0, stream, bsumB, bbase, offs);
    hipLaunchKernelGGL(k_binA, dim3(NBA), dim3(256), 0, stream,
                       src, dst, s1, s2, out1, bbase, baseA, ebA);
    hipLaunchKernelGGL(k_sortB, dim3(NBK), dim3(256), 0, stream,
                       bbase, ebA, ebB, offs);
    hipLaunchKernelGGL(k_aggregate, dim3(8 * NGRP), dim3(256), 0, stream,
                       ebB, offs, hem, out0);
}